// Round 9
// baseline (4062.246 us; speedup 1.0000x reference)
//
#include <hip/hip_runtime.h>
#include <math.h>

// NodeformerProcessor: 3x (nodeformer_conv -> [leaky] -> graph_norm).
// v7: q-side merged to 2 dispatches of 4 heads (512 thr, 54KB dyn LDS,
//     3 blocks/CU). qp' fully f32 (__expf) and G f32 -- safe by the
//     weighted-average cancellation: num/den share the same qp~, and
//     G/ksum errors are node-independent, so weight-noise perturbs the
//     output only in proportion to the deviation signal (empirically
//     bit-identical absmax through v6's f32 K-side). y accumulation and
//     num/den stay f64 (absolute noise there must stay << 1e-14 signal).
//     y written once per layer (no RMW chain). k_kv unchanged from v6.

namespace {

constexpr int N    = 50000;
constexpr int C    = 64;
constexpr int H    = 8;
constexpr int HD   = 512;
constexpr int M    = 30;

constexpr int NB2  = 160;            // k_kv blocks/head -> grid 1280 (5/CU)
constexpr int NGRP = N / 8;          // 6250 groups of 8 nodes
constexpr int PSTR = 2016;           // f32 partial: A[0,1920) Es@1920 Sv@1950 max@2014
constexpr int NBQ  = 768;            // merged k_q grid (3/CU at 512 thr)

// dynamic-LDS layout for k_q (bytes)
constexpr int OFF_KSL  = 0;          // double[120]
constexpr int OFF_RDEN = 960;        // double[32]
constexpr int OFF_P    = 1216;       // float[30*65]
constexpr int OFF_G    = 9016;       // float[4*1920]
constexpr int OFF_QS   = 39736;      // float[8*4*65]  (aliased: double red[512])
constexpr int OFF_XS   = 48056;      // float[8*65]
constexpr int OFF_QPL  = 50136;      // float[960]
constexpr int OFF_STAB = 53976;      // float[32]
constexpr int OFF_DIAG = 54104;      // float[32]
constexpr int SMEM_Q   = 54240;

__device__ constexpr double DN    = 0.35355339059327373;  // 1/sqrt(sqrt(64))
__device__ constexpr double RATIO = 0.18257418583505536;  // 1/sqrt(30)
__device__ constexpr double EPSK  = 1e-6;
__device__ constexpr double EPSN  = 1e-5;

__device__ __forceinline__ void kah(double& s, double& c, double v) {
  double y = v - c; double t = s + y; c = (t - s) - y; s = t;
}

// ------ pass 0: WP = DN * W @ P^T (f32 out), bp = DN * b @ P^T ---------------
__global__ __launch_bounds__(256)
void k_wp(const float* __restrict__ Wk, const float* __restrict__ bk,
          const float* __restrict__ P, float* __restrict__ wp,
          float* __restrict__ bp) {
  const int h = blockIdx.x, t = threadIdx.x;
  for (int s = t; s < 1920; s += 256) {
    const int m = s >> 6, c = s & 63;
    double a = 0.0;
    for (int d = 0; d < 64; ++d)
      a = fma((double)Wk[c * HD + h * 64 + d], (double)P[m * 64 + d], a);
    wp[((size_t)h * 30 + m) * 64 + c] = (float)(a * DN);
  }
  if (t < 30) {
    double a = 0.0;
    for (int d = 0; d < 64; ++d)
      a = fma((double)bk[h * 64 + d], (double)P[t * 64 + d], a);
    bp[h * 30 + t] = (float)(a * DN);
  }
}

// ------ pass 1 (f32): per-head A/Es/Sv partials + max(dd_k) ------------------
__global__ __launch_bounds__(256, 5)
void k_kv(const float* __restrict__ x32,
          const float* __restrict__ Wk, const float* __restrict__ bk,
          const float* __restrict__ Wv, const float* __restrict__ bv,
          const float* __restrict__ wp, const float* __restrict__ bp,
          float* __restrict__ partial) {
  __shared__ float wvs[4096];        // Wv slice [c][j] for this head
  __shared__ float wpk[30 * 65];     // WP_k rows, padded
  __shared__ float xs[8 * 65];       // x rows, padded (also final scratch)
  __shared__ float vsd[8 * 65];      // v rows, padded (also final scratch)
  __shared__ float kplV[240];        // E = exp(dd - diag)
  __shared__ float diag[8];
  __shared__ float bpk[30];
  const int t = threadIdx.x, i0 = t >> 6, c0 = t & 63;
  const int h = blockIdx.x / NB2, b = blockIdx.x % NB2, hb = h * 64;

  for (int s = t; s < 4096; s += 256)
    wvs[s] = Wv[(s >> 6) * HD + hb + (s & 63)];
  for (int s = t; s < 1920; s += 256)
    wpk[(s / 64) * 65 + (s & 63)] = wp[(size_t)h * 1920 + s];
  if (t < 30) bpk[t] = bp[h * 30 + t];
  const float bk0 = bk[hb + c0], bv0 = bv[hb + c0];
  float acc8[8];
#pragma unroll
  for (int k = 0; k < 8; ++k) acc8[k] = 0.0f;
  float ssv = 0.0f, ses = 0.0f, runmax = -3.0e38f;
  const int di = (t < 240) ? t / 30 : 0;
  const int dm = (t < 240) ? t - di * 30 : 0;
  __syncthreads();

  for (int g = b; g < NGRP; g += NB2) {
    const int n0 = g * 8;
    __syncthreads();  // protect xs/vsd/kplV reuse
    xs[i0 * 65 + c0]       = x32[(size_t)(n0 + i0) * C + c0];
    xs[(i0 + 4) * 65 + c0] = x32[(size_t)(n0 + i0 + 4) * C + c0];
    __syncthreads();
    float kaA = bk0, kaB = 0.f, k1A = bk0, k1B = 0.f;
    float vaA = bv0, vaB = 0.f, v1A = bv0, v1B = 0.f;
#pragma unroll 8
    for (int c = 0; c < 32; ++c) {
      const float x0a = xs[i0 * 65 + c],       x0b = xs[i0 * 65 + c + 32];
      const float x1a = xs[(i0 + 4) * 65 + c], x1b = xs[(i0 + 4) * 65 + c + 32];
      const float wka = Wk[c * HD + hb + c0];
      const float wkb = Wk[(c + 32) * HD + hb + c0];
      const float wva = wvs[c * 64 + c0];
      const float wvb = wvs[(c + 32) * 64 + c0];
      kaA = fmaf(x0a, wka, kaA); kaB = fmaf(x0b, wkb, kaB);
      k1A = fmaf(x1a, wka, k1A); k1B = fmaf(x1b, wkb, k1B);
      vaA = fmaf(x0a, wva, vaA); vaB = fmaf(x0b, wvb, vaB);
      v1A = fmaf(x1a, wva, v1A); v1B = fmaf(x1b, wvb, v1B);
    }
    const float ka0 = kaA + kaB, ka1 = k1A + k1B;
    const float va0 = vaA + vaB, va1 = v1A + v1B;
    vsd[i0 * 65 + c0] = va0; vsd[(i0 + 4) * 65 + c0] = va1;
    float q0 = ka0 * ka0, q1 = ka1 * ka1;
#pragma unroll
    for (int off = 32; off; off >>= 1) {
      q0 += __shfl_xor(q0, off, 64);
      q1 += __shfl_xor(q1, off, 64);
    }
    if (c0 == 0) {
      diag[i0]     = q0 * 0.0625f;   // DN^2/2 = 1/16
      diag[i0 + 4] = q1 * 0.0625f;
    }
    ssv += va0 + va1;  // Sv[c0] partial
    __syncthreads();
    if (t < 240) {
      float a = bpk[dm];
#pragma unroll 8
      for (int c = 0; c < 64; ++c)
        a = fmaf(xs[di * 65 + c], wpk[dm * 65 + c], a);
      runmax = fmaxf(runmax, a);
      kplV[t] = __expf(a - diag[di]);
    }
    __syncthreads();
    if (t < 30) {
      float gsum = 0.0f;
#pragma unroll
      for (int i = 0; i < 8; ++i) gsum += kplV[i * 30 + t];
      ses += gsum;
    }
#pragma unroll
    for (int k = 0; k < 8; ++k) {
      const int s = t + (k << 8);
      if (s < 1920) {
        const int m = s >> 6;
        float gsum = acc8[k];
#pragma unroll
        for (int i = 0; i < 8; ++i)
          gsum = fmaf(kplV[i * 30 + m], vsd[i * 65 + c0], gsum);
        acc8[k] = gsum;
      }
    }
  }
  const size_t base = (size_t)blockIdx.x * PSTR;
  __syncthreads();
  xs[t] = ssv;
  vsd[t] = runmax;
  __syncthreads();
  if (t < 64) partial[base + 1950 + t] = xs[t] + xs[t + 64] + xs[t + 128] + xs[t + 192];
  for (int off = 128; off; off >>= 1) {
    if (t < off) vsd[t] = fmaxf(vsd[t], vsd[t + off]);
    __syncthreads();
  }
  if (t == 0) partial[base + 2014] = vsd[0];
  if (t < 30) partial[base + 1920 + t] = ses;
#pragma unroll
  for (int k = 0; k < 8; ++k) {
    const int s = t + (k << 8);
    if (s < 1920) partial[base + s] = acc8[k];
  }
}

// ------ pass 2: reduce f32 partials in f64, apply stab/eps, G = kvs@Wo ------
__global__ __launch_bounds__(256)
void k_redkv(const float* __restrict__ partial, const float* __restrict__ Wo,
             double* __restrict__ ksumg, float* __restrict__ Gg32) {
  const int h = blockIdx.x, t = threadIdx.x;
  __shared__ float red[256];
  __shared__ double svt[64];
  __shared__ double kvls[M * 64];
  __shared__ double escs;
  const size_t hb = (size_t)h * NB2;
  red[t] = (t < NB2) ? partial[(hb + t) * PSTR + 2014] : -3.0e38f;
  __syncthreads();
  for (int off = 128; off; off >>= 1) {
    if (t < off) red[t] = fmaxf(red[t], red[t + off]);
    __syncthreads();
  }
  if (t == 0) escs = exp(-(double)red[0]);
  __syncthreads();
  const double esc = escs;
  if (t < 64) {
    double s = 0.0;
    for (int b = 0; b < NB2; ++b) s += (double)partial[(hb + b) * PSTR + 1950 + t];
    svt[t] = s;
  } else if (t < 64 + M) {
    const int m = t - 64;
    double s = 0.0;
    for (int b = 0; b < NB2; ++b) s += (double)partial[(hb + b) * PSTR + 1920 + m];
    ksumg[h * M + m] = RATIO * (esc * s + EPSK * (double)N);
  }
  __syncthreads();
#pragma unroll
  for (int k = 0; k < 8; ++k) {
    const int sidx = t + (k << 8);
    if (sidx < M * 64) {
      double s = 0.0;
      for (int b = 0; b < NB2; ++b) s += (double)partial[(hb + b) * PSTR + sidx];
      kvls[sidx] = RATIO * (esc * s + EPSK * svt[sidx & 63]);
    }
  }
  __syncthreads();
#pragma unroll
  for (int k = 0; k < 8; ++k) {
    const int sidx = t + (k << 8);
    if (sidx < M * 64) {
      const int m = sidx >> 6, c = sidx & 63;
      double a = 0.0;
      for (int d = 0; d < 64; ++d)
        a = fma(kvls[m * 64 + d], (double)Wo[(h * 64 + d) * 64 + c], a);
      Gg32[(size_t)h * 1920 + sidx] = (float)a;   // f32 G: node-consistent error
    }
  }
}

// ------ pass 3 (x2, 4 heads each): q -> qp'(f32) -> y += qp' @ G (f64) -------
// MODE 0: init y = bo + contrib(H0..H0+3); MODE 1: y += contrib, leaky, colsums
template <int MODE>
__global__ __launch_bounds__(512)
void k_q(const float* __restrict__ x32,
         const float* __restrict__ Wq, const float* __restrict__ bq,
         const float* __restrict__ P, const double* __restrict__ ksumg,
         const float* __restrict__ Gg32, const float* __restrict__ bo,
         int do_leaky, int H0,
         double* __restrict__ y, double* __restrict__ psum) {
  extern __shared__ char smem[];
  double* ksl   = (double*)(smem + OFF_KSL);    // [4][30]
  double* rdend = (double*)(smem + OFF_RDEN);   // [8*4]
  float*  Pl    = (float*)(smem + OFF_P);       // [30][65], DN folded in
  float*  Gl    = (float*)(smem + OFF_G);       // [4][1920]
  float*  qs    = (float*)(smem + OFF_QS);      // [8][4][65]
  double* red   = (double*)(smem + OFF_QS);     // [512] alias (used after loop)
  float*  xs    = (float*)(smem + OFF_XS);      // [8][65]
  float*  qpl   = (float*)(smem + OFF_QPL);     // [8*4*30]
  float*  stabd = (float*)(smem + OFF_STAB);    // [8*4]
  float*  diagd = (float*)(smem + OFF_DIAG);    // [8*4]
  const int t = threadIdx.x, i0 = t >> 6, c0 = t & 63;

  for (int s = t; s < 1920; s += 512)
    Pl[(s >> 6) * 65 + (s & 63)] = (float)DN * P[s];
  for (int s = t; s < 7680; s += 512) {
    const int hh = s / 1920;
    Gl[s] = Gg32[(size_t)(H0 + hh) * 1920 + (s - hh * 1920)];
  }
  if (t < 120) ksl[t] = ksumg[(H0 + t / 30) * 30 + (t % 30)];
  const double bo0 = (double)bo[c0];
  float bq4[4];
#pragma unroll
  for (int hh = 0; hh < 4; ++hh) bq4[hh] = bq[(H0 + hh) * 64 + c0];
  double sy = 0.0, sy2 = 0.0;
  __syncthreads();

  for (int g = blockIdx.x; g < NGRP; g += NBQ) {
    const int n0 = g * 8;
    xs[i0 * 65 + c0] = x32[(size_t)(n0 + i0) * C + c0];
    __syncthreads();
    // q projection: 1 node, 4 heads per thread (f32, Wq from L1/L2)
    float aq[4];
#pragma unroll
    for (int hh = 0; hh < 4; ++hh) aq[hh] = bq4[hh];
#pragma unroll 8
    for (int c = 0; c < 64; ++c) {
      const float xv = xs[i0 * 65 + c];
#pragma unroll
      for (int hh = 0; hh < 4; ++hh)
        aq[hh] = fmaf(xv, Wq[c * HD + (H0 + hh) * 64 + c0], aq[hh]);
    }
#pragma unroll
    for (int hh = 0; hh < 4; ++hh) {
      qs[i0 * 260 + hh * 65 + c0] = aq[hh];
      float s = aq[hh] * aq[hh];
#pragma unroll
      for (int off = 32; off; off >>= 1) s += __shfl_xor(s, off, 64);
      if (c0 == 0) diagd[i0 * 4 + hh] = s * 0.0625f;   // DN^2/2
    }
    __syncthreads();
    // dd (raw) = q . (DN*P)
#pragma unroll
    for (int rep = 0; rep < 2; ++rep) {
      const int item = t + rep * 512;
      if (item < 960) {
        const int i = item / 120, r = item - i * 120, hh = r / 30, m = r - hh * 30;
        float a = 0.0f;
#pragma unroll 8
        for (int d = 0; d < 64; ++d)
          a = fmaf(qs[i * 260 + hh * 65 + d], Pl[m * 65 + d], a);
        qpl[item] = a;
      }
    }
    __syncthreads();
    if (t < 32) {  // stab = max over m of raw dd
      const float* q = qpl + t * 30;
      float mx = q[0];
      for (int m = 1; m < 30; ++m) mx = fmaxf(mx, q[m]);
      stabd[t] = mx;
    }
    __syncthreads();
#pragma unroll
    for (int rep = 0; rep < 2; ++rep) {  // qp' in-place (f32)
      const int item = t + rep * 512;
      if (item < 960) {
        const int ih = item / 30;
        qpl[item] = 0.18257418583505536f *
                    (__expf((qpl[item] - diagd[ih]) - stabd[ih]) + 1e-6f);
      }
    }
    __syncthreads();
    if (t < 32) {  // den in f64 from the SAME qp' (cancellation-exact weights)
      double den = 0.0;
      const float* q = qpl + t * 30;
      const double* ks = ksl + (t & 3) * 30;
      for (int m = 0; m < 30; ++m) den = fma((double)q[m], ks[m], den);
      rdend[t] = 1.0 / den;
    }
    __syncthreads();
    // y element (i0, c0): f64 accumulation over 4 heads x 30 m
    double acc = 0.0;
#pragma unroll
    for (int hh = 0; hh < 4; ++hh) {
      const float* qp = qpl + (i0 * 4 + hh) * 30;
      const float* gp = Gl + hh * 1920 + c0;
      double s = 0.0;
      for (int m = 0; m < 30; ++m)
        s = fma((double)qp[m], (double)gp[m * 64], s);
      acc = fma(s, rdend[i0 * 4 + hh], acc);
    }
    const size_t yi = (size_t)(n0 + i0) * C + c0;
    if (MODE == 0) {
      y[yi] = bo0 + acc;
    } else {
      double v = y[yi] + acc;
      if (do_leaky) v = (v >= 0.0) ? v : 0.01 * v;
      y[yi] = v;
      sy += v;
      sy2 = fma(v, v, sy2);
    }
    __syncthreads();  // qpl/rdend reads done before next iter's overwrites
  }
  if (MODE == 1) {  // block column sums (qs region dead -> reuse as f64 red)
    __syncthreads();
    red[t] = sy;
    __syncthreads();
    if (t < 64) {
      double s = 0.0;
      for (int w = 0; w < 8; ++w) s += red[c0 + 64 * w];
      psum[(size_t)blockIdx.x * 128 + c0] = s;
    }
    __syncthreads();
    red[t] = sy2;
    __syncthreads();
    if (t < 64) {
      double s = 0.0;
      for (int w = 0; w < 8; ++w) s += red[c0 + 64 * w];
      psum[(size_t)blockIdx.x * 128 + 64 + c0] = s;
    }
  }
}

// ------ graph-norm parameters ------------------------------------------------
__global__ void k_norm_params(const double* __restrict__ psum,
                              const float* __restrict__ gamma, const float* __restrict__ beta,
                              const float* __restrict__ alpha, double* __restrict__ nparam) {
  const int t = threadIdx.x;
  __shared__ double m1l[64], m2l[64];
  if (t < 64) {
    double s = 0, c = 0;
    for (int b = 0; b < NBQ; ++b) kah(s, c, psum[(size_t)b * 128 + t]);
    m1l[t] = s - c;
  } else if (t < 128) {
    const int ci = t - 64;
    double s = 0, c = 0;
    for (int b = 0; b < NBQ; ++b) kah(s, c, psum[(size_t)b * 128 + 64 + ci]);
    m2l[ci] = s - c;
  }
  __syncthreads();
  if (t < 64) {
    const double mu = m1l[t] / (double)N;
    const double m2 = m2l[t] / (double)N;
    const double al = (double)alpha[t];
    double var = m2 - (2.0 * al - al * al) * mu * mu;
    if (var < 0.0) var = 0.0;
    nparam[t]       = al * mu;
    nparam[64 + t]  = (double)gamma[t] / sqrt(var + EPSN);
    nparam[128 + t] = (double)beta[t];
  }
}

// ------ normalize y -> f32 (next-layer x32, or final output) -----------------
__global__ void k_cast(const double* __restrict__ yv, const double* __restrict__ nparam,
                       float* __restrict__ dst) {
  const int total = N * C;
  for (int i = blockIdx.x * blockDim.x + threadIdx.x; i < total; i += gridDim.x * blockDim.x) {
    const int c = i & 63;
    dst[i] = (float)((yv[i] - nparam[c]) * nparam[64 + c] + nparam[128 + c]);
  }
}

}  // namespace

extern "C" void kernel_launch(void* const* d_in, const int* in_sizes, int n_in,
                              void* d_out, int out_size, void* d_ws, size_t ws_size,
                              hipStream_t stream) {
  const float* patch = (const float*)d_in[0];
  // d_in[1] edge_index, d_in[2] edge_attr: unused by the reference
  const float* Wq = (const float*)d_in[3];
  const float* Wk = (const float*)d_in[4];
  const float* Wv = (const float*)d_in[5];
  const float* Wo = (const float*)d_in[6];
  const float* bq = (const float*)d_in[7];
  const float* bk = (const float*)d_in[8];
  const float* bv = (const float*)d_in[9];
  const float* bo = (const float*)d_in[10];
  const float* P  = (const float*)d_in[11];
  const float* ga = (const float*)d_in[12];
  const float* be = (const float*)d_in[13];
  const float* al = (const float*)d_in[14];
  float* out = (float*)d_out;

  // workspace (~56 MB): f64 first (alignment), then f32
  char* wsb = (char*)d_ws;
  double* y      = (double*)wsb;   wsb += (size_t)N * C * 8;              // 25.6MB
  double* psum   = (double*)wsb;   wsb += (size_t)NBQ * 128 * 8;          // 786KB
  double* nparam = (double*)wsb;   wsb += 192 * 8;
  double* ksumg  = (double*)wsb;   wsb += (size_t)H * M * 8;
  float*  x32    = (float*)wsb;    wsb += (size_t)N * C * 4;              // 12.8MB
  float*  partial= (float*)wsb;    wsb += (size_t)(H * NB2) * PSTR * 4;   // 10.3MB
  float*  G32    = (float*)wsb;    wsb += (size_t)H * M * 64 * 4;         // 61KB
  float*  wpf    = (float*)wsb;    wsb += (size_t)H * M * 64 * 4;
  float*  bpf    = (float*)wsb;    wsb += (size_t)H * M * 4;

  for (int L = 0; L < 3; ++L) {
    const float* wq  = Wq + (size_t)L * C * HD;
    const float* wk  = Wk + (size_t)L * C * HD;
    const float* wv  = Wv + (size_t)L * C * HD;
    const float* wo  = Wo + (size_t)L * HD * C;
    const float* bq_ = bq + (size_t)L * HD;
    const float* bk_ = bk + (size_t)L * HD;
    const float* bv_ = bv + (size_t)L * HD;
    const float* bo_ = bo + (size_t)L * C;
    const float* p   = P  + (size_t)L * M * C;
    const int leaky = (L < 2) ? 1 : 0;
    const float* xcur = (L == 0) ? patch : x32;

    k_wp<<<H, 256, 0, stream>>>(wk, bk_, p, wpf, bpf);
    k_kv<<<H * NB2, 256, 0, stream>>>(xcur, wk, bk_, wv, bv_, wpf, bpf, partial);
    k_redkv<<<H, 256, 0, stream>>>(partial, wo, ksumg, G32);

    k_q<0><<<NBQ, 512, SMEM_Q, stream>>>(xcur, wq, bq_, p, ksumg, G32, bo_,
                                         leaky, 0, y, psum);
    k_q<1><<<NBQ, 512, SMEM_Q, stream>>>(xcur, wq, bq_, p, ksumg, G32, bo_,
                                         leaky, 4, y, psum);

    k_norm_params<<<1, 128, 0, stream>>>(psum, ga + (size_t)L * C, be + (size_t)L * C,
                                         al + (size_t)L * C, nparam);
    k_cast<<<512, 256, 0, stream>>>(y, nparam, (L < 2) ? x32 : out);
  }
}

// Round 10
// 2292.943 us; speedup vs baseline: 1.7716x; 1.7716x over previous
//
#include <hip/hip_runtime.h>
#include <math.h>

// NodeformerProcessor: 3x (nodeformer_conv -> [leaky] -> graph_norm).
// v8: occupancy-exact relaunch of the v6 structure.
//     - k_q: 2 heads/dispatch (4 dispatches/layer: MODE 0 init, 1 add, 2 final),
//       LDS 38.9KB -> 4 blocks/CU pinned, grid 1024, Wq slice L1-resident.
//       dd via WP (v6 math), qp'/G f32 (v7-validated), den/y f64.
//     - k_kv: 16-node groups (half the barriers/node), float4 LDS reads
//       (rows padded to 68 floats = 16B aligned), vsd hoisted to registers.
//       LDS 34.5KB -> 4 blocks/CU, grid 1024.
//     All reductions fixed-order, no atomics. ws ~48MB.

namespace {

constexpr int N    = 50000;
constexpr int C    = 64;
constexpr int H    = 8;
constexpr int HD   = 512;
constexpr int M    = 30;

constexpr int NBK  = 128;            // k_kv blocks per head -> grid 1024 (4/CU)
constexpr int NGK  = N / 16;         // 3125 groups of 16 nodes
constexpr int NBQ  = 1024;           // k_q grid (4/CU)
constexpr int NGQ8 = N / 8;          // 6250 groups of 8 nodes
constexpr int PSTR = 2016;           // f32 partial: A[0,1920) Es@1920 Sv@1950 max@2014

__device__ constexpr double DN    = 0.35355339059327373;  // 1/sqrt(sqrt(64))
__device__ constexpr double RATIO = 0.18257418583505536;  // 1/sqrt(30)
__device__ constexpr double EPSK  = 1e-6;
__device__ constexpr double EPSN  = 1e-5;

__device__ __forceinline__ void kah(double& s, double& c, double v) {
  double y = v - c; double t = s + y; c = (t - s) - y; s = t;
}

// ------ pass 0: WP[side][h] = DN * W @ P^T (f32), bp = DN * b @ P^T ----------
__global__ __launch_bounds__(256)
void k_wp(const float* __restrict__ Wk, const float* __restrict__ bk,
          const float* __restrict__ Wq, const float* __restrict__ bq,
          const float* __restrict__ P, float* __restrict__ wp,
          float* __restrict__ bp) {
  const int blk = blockIdx.x, side = blk >> 3, h = blk & 7, t = threadIdx.x;
  const float* W  = side ? Wq : Wk;
  const float* bb = side ? bq : bk;
  for (int s = t; s < 1920; s += 256) {
    const int m = s >> 6, c = s & 63;
    double a = 0.0;
    for (int d = 0; d < 64; ++d)
      a = fma((double)W[c * HD + h * 64 + d], (double)P[m * 64 + d], a);
    wp[((size_t)(side * 8 + h) * 30 + m) * 64 + c] = (float)(a * DN);
  }
  if (t < 30) {
    double a = 0.0;
    for (int d = 0; d < 64; ++d)
      a = fma((double)bb[h * 64 + d], (double)P[t * 64 + d], a);
    bp[(side * 8 + h) * 30 + t] = (float)(a * DN);
  }
}

// ------ pass 1 (f32): per-head A/Es/Sv partials + max(dd_k), 16 nodes/iter ---
__global__ __launch_bounds__(256, 4)
void k_kv(const float* __restrict__ x32,
          const float* __restrict__ Wk, const float* __restrict__ bk,
          const float* __restrict__ Wv, const float* __restrict__ bv,
          const float* __restrict__ wp, const float* __restrict__ bp,
          float* __restrict__ partial) {
  __shared__ __align__(16) float wvs[4096];       // Wv slice [c][j]
  __shared__ __align__(16) float wpk[30 * 68];    // WP_k rows, 16B-aligned
  __shared__ __align__(16) float xs[16 * 68];     // x rows (also final scratch)
  __shared__ __align__(16) float vsd[16 * 68];    // v rows (also final scratch)
  __shared__ float kplV[480];                     // E = exp(dd - diag)
  __shared__ float diag[16];
  __shared__ float bpk[30];
  const int t = threadIdx.x, i0 = t >> 6, c0 = t & 63;
  const int h = blockIdx.x >> 7, b = blockIdx.x & (NBK - 1), hb = h * 64;

  for (int s = t; s < 4096; s += 256)
    wvs[s] = Wv[(s >> 6) * HD + hb + (s & 63)];
  for (int s = t; s < 1920; s += 256)
    wpk[(s >> 6) * 68 + (s & 63)] = wp[(size_t)h * 1920 + s];
  if (t < 30) bpk[t] = bp[h * 30 + t];
  const float bk0 = bk[hb + c0], bv0 = bv[hb + c0];
  float acc8[8];
#pragma unroll
  for (int k = 0; k < 8; ++k) acc8[k] = 0.0f;
  float ssv = 0.0f, ses = 0.0f, runmax = -3.0e38f;
  __syncthreads();

  for (int g = b; g < NGK; g += NBK) {
    const int n0 = g * 16;
    __syncthreads();  // protect xs/vsd/kplV reuse
#pragma unroll
    for (int u = 0; u < 4; ++u)
      xs[(i0 + 4 * u) * 68 + c0] = x32[(size_t)(n0 + i0 + 4 * u) * C + c0];
    __syncthreads();
    // k,v projection: 4 nodes/thread, float4 x reads, 8 independent chains
    float ka[4], va[4];
#pragma unroll
    for (int u = 0; u < 4; ++u) { ka[u] = bk0; va[u] = bv0; }
#pragma unroll 4
    for (int c4 = 0; c4 < 16; ++c4) {
      float4 xv[4];
#pragma unroll
      for (int u = 0; u < 4; ++u)
        xv[u] = reinterpret_cast<const float4*>(xs + (i0 + 4 * u) * 68)[c4];
#pragma unroll
      for (int j = 0; j < 4; ++j) {
        const int c = c4 * 4 + j;
        const float wk_ = Wk[c * HD + hb + c0];
        const float wv_ = wvs[c * 64 + c0];
        const float xj0 = (j == 0) ? xv[0].x : (j == 1) ? xv[0].y : (j == 2) ? xv[0].z : xv[0].w;
        const float xj1 = (j == 0) ? xv[1].x : (j == 1) ? xv[1].y : (j == 2) ? xv[1].z : xv[1].w;
        const float xj2 = (j == 0) ? xv[2].x : (j == 1) ? xv[2].y : (j == 2) ? xv[2].z : xv[2].w;
        const float xj3 = (j == 0) ? xv[3].x : (j == 1) ? xv[3].y : (j == 2) ? xv[3].z : xv[3].w;
        ka[0] = fmaf(xj0, wk_, ka[0]); va[0] = fmaf(xj0, wv_, va[0]);
        ka[1] = fmaf(xj1, wk_, ka[1]); va[1] = fmaf(xj1, wv_, va[1]);
        ka[2] = fmaf(xj2, wk_, ka[2]); va[2] = fmaf(xj2, wv_, va[2]);
        ka[3] = fmaf(xj3, wk_, ka[3]); va[3] = fmaf(xj3, wv_, va[3]);
      }
    }
#pragma unroll
    for (int u = 0; u < 4; ++u) {
      vsd[(i0 + 4 * u) * 68 + c0] = va[u];
      float s = ka[u] * ka[u];
#pragma unroll
      for (int off = 32; off; off >>= 1) s += __shfl_xor(s, off, 64);
      if (c0 == 0) diag[i0 + 4 * u] = s * 0.0625f;   // DN^2/2
      ssv += va[u];
    }
    __syncthreads();
    // dd_k via WP (float4), max track, E = exp(dd - diag)
#pragma unroll
    for (int rep = 0; rep < 2; ++rep) {
      const int item = t + rep * 256;
      if (item < 480) {
        const int di = item / 30, dm = item - di * 30;
        float a = bpk[dm];
#pragma unroll 4
        for (int c4 = 0; c4 < 16; ++c4) {
          const float4 xv = reinterpret_cast<const float4*>(xs + di * 68)[c4];
          const float4 wv = reinterpret_cast<const float4*>(wpk + dm * 68)[c4];
          a = fmaf(xv.x, wv.x, a); a = fmaf(xv.y, wv.y, a);
          a = fmaf(xv.z, wv.z, a); a = fmaf(xv.w, wv.w, a);
        }
        runmax = fmaxf(runmax, a);
        kplV[item] = __expf(a - diag[di]);
      }
    }
    __syncthreads();
    if (t < 30) {  // Es[m] partial
      float gsum = 0.0f;
#pragma unroll
      for (int i = 0; i < 16; ++i) gsum += kplV[i * 30 + t];
      ses += gsum;
    }
    // A[m][c0] += E[i][m]*v[i][c0], vsd hoisted
    float vr[16];
#pragma unroll
    for (int i = 0; i < 16; ++i) vr[i] = vsd[i * 68 + c0];
#pragma unroll
    for (int k = 0; k < 8; ++k) {
      const int s = t + (k << 8);
      if (s < 1920) {
        const int m = s >> 6;
        float gsum = acc8[k];
#pragma unroll
        for (int i = 0; i < 16; ++i)
          gsum = fmaf(kplV[i * 30 + m], vr[i], gsum);
        acc8[k] = gsum;
      }
    }
  }
  // block outputs (reuse xs / vsd as scratch)
  const size_t base = (size_t)blockIdx.x * PSTR;
  __syncthreads();
  xs[t] = ssv;
  vsd[t] = runmax;
  __syncthreads();
  if (t < 64) partial[base + 1950 + t] = xs[t] + xs[t + 64] + xs[t + 128] + xs[t + 192];
  for (int off = 128; off; off >>= 1) {
    if (t < off) vsd[t] = fmaxf(vsd[t], vsd[t + off]);
    __syncthreads();
  }
  if (t == 0) partial[base + 2014] = vsd[0];
  if (t < 30) partial[base + 1920 + t] = ses;
#pragma unroll
  for (int k = 0; k < 8; ++k) {
    const int s = t + (k << 8);
    if (s < 1920) partial[base + s] = acc8[k];
  }
}

// ------ pass 2: reduce f32 partials in f64, apply stab/eps, G = kvs@Wo ------
__global__ __launch_bounds__(256)
void k_redkv(const float* __restrict__ partial, const float* __restrict__ Wo,
             double* __restrict__ ksumg, float* __restrict__ Gg32) {
  const int h = blockIdx.x, t = threadIdx.x;
  __shared__ float red[256];
  __shared__ double svt[64];
  __shared__ double kvls[M * 64];
  __shared__ double escs;
  const size_t hb = (size_t)h * NBK;
  red[t] = (t < NBK) ? partial[(hb + t) * PSTR + 2014] : -3.0e38f;
  __syncthreads();
  for (int off = 128; off; off >>= 1) {
    if (t < off) red[t] = fmaxf(red[t], red[t + off]);
    __syncthreads();
  }
  if (t == 0) escs = exp(-(double)red[0]);
  __syncthreads();
  const double esc = escs;
  if (t < 64) {
    double s = 0.0;
    for (int b = 0; b < NBK; ++b) s += (double)partial[(hb + b) * PSTR + 1950 + t];
    svt[t] = s;
  } else if (t < 64 + M) {
    const int m = t - 64;
    double s = 0.0;
    for (int b = 0; b < NBK; ++b) s += (double)partial[(hb + b) * PSTR + 1920 + m];
    ksumg[h * M + m] = RATIO * (esc * s + EPSK * (double)N);
  }
  __syncthreads();
#pragma unroll
  for (int k = 0; k < 8; ++k) {
    const int sidx = t + (k << 8);
    if (sidx < M * 64) {
      double s = 0.0;
      for (int b = 0; b < NBK; ++b) s += (double)partial[(hb + b) * PSTR + sidx];
      kvls[sidx] = RATIO * (esc * s + EPSK * svt[sidx & 63]);
    }
  }
  __syncthreads();
#pragma unroll
  for (int k = 0; k < 8; ++k) {
    const int sidx = t + (k << 8);
    if (sidx < M * 64) {
      const int m = sidx >> 6, c = sidx & 63;
      double a = 0.0;
      for (int d = 0; d < 64; ++d)
        a = fma(kvls[m * 64 + d], (double)Wo[(h * 64 + d) * 64 + c], a);
      Gg32[(size_t)h * 1920 + sidx] = (float)a;
    }
  }
}

// ------ pass 3 (x4, 2 heads each): q-front f32 -> y += qp' @ G (f64) ---------
// MODE 0: y = bo + contrib; MODE 1: y += contrib; MODE 2: final (+leaky+colsums)
template <int MODE>
__global__ __launch_bounds__(256, 4)
void k_q(const float* __restrict__ x32,
         const float* __restrict__ Wq, const float* __restrict__ bq,
         const float* __restrict__ wp, const float* __restrict__ bp,
         const double* __restrict__ ksumg, const float* __restrict__ Gg32,
         const float* __restrict__ bo, int do_leaky, int H0,
         double* __restrict__ y, double* __restrict__ psum) {
  __shared__ __align__(16) float wpq[2][30 * 68];  // WP_q rows, 16B-aligned
  __shared__ float Gl[2][1920];
  __shared__ __align__(16) float xs[8 * 68];
  __shared__ float qpl[480];                       // raw dd, then qp'
  __shared__ float stabd[16], diagd[16];
  __shared__ double ksl[2][30];
  __shared__ double rdend[16];
  __shared__ float bpq2[2][30];
  __shared__ double red[256];
  const int t = threadIdx.x, i0 = t >> 6, c0 = t & 63;

  for (int s = t; s < 3840; s += 256) {
    const int hh = s / 1920, r = s - hh * 1920, m = r >> 6, c = r & 63;
    wpq[hh][m * 68 + c] = wp[(size_t)(8 + H0 + hh) * 1920 + r];
    Gl[hh][r] = Gg32[(size_t)(H0 + hh) * 1920 + r];
  }
  if (t < 60) {
    ksl[t / 30][t % 30]  = ksumg[(H0 + t / 30) * 30 + (t % 30)];
    bpq2[t / 30][t % 30] = bp[(8 + H0 + t / 30) * 30 + (t % 30)];
  }
  const float bqA = bq[H0 * 64 + c0];
  const float bqB = bq[H0 * 64 + 64 + c0];
  const double bo0 = (double)bo[c0];
  double sy = 0.0, sy2 = 0.0;
  __syncthreads();

  for (int g = blockIdx.x; g < NGQ8; g += NBQ) {
    const int n0 = g * 8;
    __syncthreads();  // protect xs/qpl reuse
    xs[i0 * 68 + c0]       = x32[(size_t)(n0 + i0) * C + c0];
    xs[(i0 + 4) * 68 + c0] = x32[(size_t)(n0 + i0 + 4) * C + c0];
    __syncthreads();
    // q projection (diag only): 2 heads x 2 nodes, Wq slice L1-resident (32KB)
    float aq0 = bqA, aq1 = bqB, aq2 = bqA, aq3 = bqB;
#pragma unroll 4
    for (int c4 = 0; c4 < 16; ++c4) {
      const float4 xa = reinterpret_cast<const float4*>(xs + i0 * 68)[c4];
      const float4 xb = reinterpret_cast<const float4*>(xs + (i0 + 4) * 68)[c4];
#pragma unroll
      for (int j = 0; j < 4; ++j) {
        const int c = c4 * 4 + j;
        const float wA = Wq[c * HD + H0 * 64 + c0];
        const float wB = Wq[c * HD + H0 * 64 + 64 + c0];
        const float xaj = (j == 0) ? xa.x : (j == 1) ? xa.y : (j == 2) ? xa.z : xa.w;
        const float xbj = (j == 0) ? xb.x : (j == 1) ? xb.y : (j == 2) ? xb.z : xb.w;
        aq0 = fmaf(xaj, wA, aq0); aq1 = fmaf(xaj, wB, aq1);
        aq2 = fmaf(xbj, wA, aq2); aq3 = fmaf(xbj, wB, aq3);
      }
    }
    {
      float s0 = aq0 * aq0, s1 = aq1 * aq1, s2 = aq2 * aq2, s3 = aq3 * aq3;
#pragma unroll
      for (int off = 32; off; off >>= 1) {
        s0 += __shfl_xor(s0, off, 64); s1 += __shfl_xor(s1, off, 64);
        s2 += __shfl_xor(s2, off, 64); s3 += __shfl_xor(s3, off, 64);
      }
      if (c0 == 0) {
        diagd[i0 * 2]           = s0 * 0.0625f;
        diagd[i0 * 2 + 1]       = s1 * 0.0625f;
        diagd[(i0 + 4) * 2]     = s2 * 0.0625f;
        diagd[(i0 + 4) * 2 + 1] = s3 * 0.0625f;
      }
    }
    // dd_q raw via WP (float4)
#pragma unroll
    for (int rep = 0; rep < 2; ++rep) {
      const int item = t + rep * 256;
      if (item < 480) {
        const int i = item / 60, r = item - i * 60, hh = r / 30, m = r - hh * 30;
        float a = bpq2[hh][m];
#pragma unroll 4
        for (int c4 = 0; c4 < 16; ++c4) {
          const float4 xv = reinterpret_cast<const float4*>(xs + i * 68)[c4];
          const float4 wv = reinterpret_cast<const float4*>(wpq[hh] + m * 68)[c4];
          a = fmaf(xv.x, wv.x, a); a = fmaf(xv.y, wv.y, a);
          a = fmaf(xv.z, wv.z, a); a = fmaf(xv.w, wv.w, a);
        }
        qpl[item] = a;  // item == (i*2+hh)*30 + m
      }
    }
    __syncthreads();
    if (t < 16) {  // stab = max over m of raw dd
      const float* q = qpl + t * 30;
      float mx = q[0];
      for (int m = 1; m < 30; ++m) mx = fmaxf(mx, q[m]);
      stabd[t] = mx;
    }
    __syncthreads();
#pragma unroll
    for (int rep = 0; rep < 2; ++rep) {  // qp' in place (f32)
      const int item = t + rep * 256;
      if (item < 480) {
        const int ih = item / 30;
        qpl[item] = 0.18257418583505536f *
                    (__expf((qpl[item] - diagd[ih]) - stabd[ih]) + 1e-6f);
      }
    }
    __syncthreads();
    if (t < 16) {  // den f64 from the same qp'
      double den = 0.0;
      const float* q = qpl + t * 30;
      const double* ks = ksl[t & 1];
      for (int m = 0; m < 30; ++m) den = fma((double)q[m], ks[m], den);
      rdend[t] = 1.0 / den;
    }
    __syncthreads();
    // y apply: nodes i0, i0+4 at column c0 (f64)
    double acc_a = 0.0, acc_b = 0.0;
#pragma unroll
    for (int hh = 0; hh < 2; ++hh) {
      const float* qa = qpl + (i0 * 2 + hh) * 30;
      const float* qb = qpl + ((i0 + 4) * 2 + hh) * 30;
      const float* g  = Gl[hh] + c0;
      double sa = 0.0, sb = 0.0;
      for (int m = 0; m < 30; ++m) {
        const double gv = (double)g[m * 64];
        sa = fma((double)qa[m], gv, sa);
        sb = fma((double)qb[m], gv, sb);
      }
      acc_a = fma(sa, rdend[i0 * 2 + hh], acc_a);
      acc_b = fma(sb, rdend[(i0 + 4) * 2 + hh], acc_b);
    }
    const size_t ia = (size_t)(n0 + i0) * C + c0;
    const size_t ib = (size_t)(n0 + i0 + 4) * C + c0;
    if (MODE == 0) {
      y[ia] = bo0 + acc_a;
      y[ib] = bo0 + acc_b;
    } else if (MODE == 1) {
      y[ia] += acc_a;
      y[ib] += acc_b;
    } else {
      double va = y[ia] + acc_a, vb = y[ib] + acc_b;
      if (do_leaky) {
        va = (va >= 0.0) ? va : 0.01 * va;
        vb = (vb >= 0.0) ? vb : 0.01 * vb;
      }
      y[ia] = va; y[ib] = vb;
      sy += va + vb;
      sy2 = fma(va, va, sy2);
      sy2 = fma(vb, vb, sy2);
    }
  }
  if (MODE == 2) {  // block column sums
    __syncthreads();
    red[t] = sy;
    __syncthreads();
    if (t < 64) psum[(size_t)blockIdx.x * 128 + t] =
        red[t] + red[t + 64] + red[t + 128] + red[t + 192];
    __syncthreads();
    red[t] = sy2;
    __syncthreads();
    if (t < 64) psum[(size_t)blockIdx.x * 128 + 64 + t] =
        red[t] + red[t + 64] + red[t + 128] + red[t + 192];
  }
}

// ------ graph-norm parameters ------------------------------------------------
__global__ void k_norm_params(const double* __restrict__ psum,
                              const float* __restrict__ gamma, const float* __restrict__ beta,
                              const float* __restrict__ alpha, double* __restrict__ nparam) {
  const int t = threadIdx.x;
  __shared__ double m1l[64], m2l[64];
  if (t < 64) {
    double s = 0, c = 0;
    for (int b = 0; b < NBQ; ++b) kah(s, c, psum[(size_t)b * 128 + t]);
    m1l[t] = s - c;
  } else if (t < 128) {
    const int ci = t - 64;
    double s = 0, c = 0;
    for (int b = 0; b < NBQ; ++b) kah(s, c, psum[(size_t)b * 128 + 64 + ci]);
    m2l[ci] = s - c;
  }
  __syncthreads();
  if (t < 64) {
    const double mu = m1l[t] / (double)N;
    const double m2 = m2l[t] / (double)N;
    const double al = (double)alpha[t];
    double var = m2 - (2.0 * al - al * al) * mu * mu;
    if (var < 0.0) var = 0.0;
    nparam[t]       = al * mu;
    nparam[64 + t]  = (double)gamma[t] / sqrt(var + EPSN);
    nparam[128 + t] = (double)beta[t];
  }
}

// ------ normalize y -> f32 (next-layer x32, or final output) -----------------
__global__ void k_cast(const double* __restrict__ yv, const double* __restrict__ nparam,
                       float* __restrict__ dst) {
  const int total = N * C;
  for (int i = blockIdx.x * blockDim.x + threadIdx.x; i < total; i += gridDim.x * blockDim.x) {
    const int c = i & 63;
    dst[i] = (float)((yv[i] - nparam[c]) * nparam[64 + c] + nparam[128 + c]);
  }
}

}  // namespace

extern "C" void kernel_launch(void* const* d_in, const int* in_sizes, int n_in,
                              void* d_out, int out_size, void* d_ws, size_t ws_size,
                              hipStream_t stream) {
  const float* patch = (const float*)d_in[0];
  // d_in[1] edge_index, d_in[2] edge_attr: unused by the reference
  const float* Wq = (const float*)d_in[3];
  const float* Wk = (const float*)d_in[4];
  const float* Wv = (const float*)d_in[5];
  const float* Wo = (const float*)d_in[6];
  const float* bq = (const float*)d_in[7];
  const float* bk = (const float*)d_in[8];
  const float* bv = (const float*)d_in[9];
  const float* bo = (const float*)d_in[10];
  const float* P  = (const float*)d_in[11];
  const float* ga = (const float*)d_in[12];
  const float* be = (const float*)d_in[13];
  const float* al = (const float*)d_in[14];
  float* out = (float*)d_out;

  // workspace (~48 MB): f64 first (alignment), then f32
  char* wsb = (char*)d_ws;
  double* y      = (double*)wsb;   wsb += (size_t)N * C * 8;               // 25.6MB
  double* psum   = (double*)wsb;   wsb += (size_t)NBQ * 128 * 8;           // 1.0MB
  double* nparam = (double*)wsb;   wsb += 192 * 8;
  double* ksumg  = (double*)wsb;   wsb += (size_t)H * M * 8;
  float*  x32    = (float*)wsb;    wsb += (size_t)N * C * 4;               // 12.8MB
  float*  partial= (float*)wsb;    wsb += (size_t)(H * NBK) * PSTR * 4;    // 8.3MB
  float*  G32    = (float*)wsb;    wsb += (size_t)H * M * 64 * 4;          // 61KB
  float*  wpf    = (float*)wsb;    wsb += (size_t)2 * H * M * 64 * 4;      // 123KB
  float*  bpf    = (float*)wsb;    wsb += (size_t)2 * H * M * 4;

  for (int L = 0; L < 3; ++L) {
    const float* wq  = Wq + (size_t)L * C * HD;
    const float* wk  = Wk + (size_t)L * C * HD;
    const float* wv  = Wv + (size_t)L * C * HD;
    const float* wo  = Wo + (size_t)L * HD * C;
    const float* bq_ = bq + (size_t)L * HD;
    const float* bk_ = bk + (size_t)L * HD;
    const float* bv_ = bv + (size_t)L * HD;
    const float* bo_ = bo + (size_t)L * C;
    const float* p   = P  + (size_t)L * M * C;
    const int leaky = (L < 2) ? 1 : 0;
    const float* xcur = (L == 0) ? patch : x32;

    k_wp<<<16, 256, 0, stream>>>(wk, bk_, wq, bq_, p, wpf, bpf);
    k_kv<<<H * NBK, 256, 0, stream>>>(xcur, wk, bk_, wv, bv_, wpf, bpf, partial);
    k_redkv<<<H, 256, 0, stream>>>(partial, wo, ksumg, G32);

    k_q<0><<<NBQ, 256, 0, stream>>>(xcur, wq, bq_, wpf, bpf, ksumg, G32, bo_,
                                    leaky, 0, y, psum);
    k_q<1><<<NBQ, 256, 0, stream>>>(xcur, wq, bq_, wpf, bpf, ksumg, G32, bo_,
                                    leaky, 2, y, psum);
    k_q<1><<<NBQ, 256, 0, stream>>>(xcur, wq, bq_, wpf, bpf, ksumg, G32, bo_,
                                    leaky, 4, y, psum);
    k_q<2><<<NBQ, 256, 0, stream>>>(xcur, wq, bq_, wpf, bpf, ksumg, G32, bo_,
                                    leaky, 6, y, psum);

    k_norm_params<<<1, 128, 0, stream>>>(psum, ga + (size_t)L * C, be + (size_t)L * C,
                                         al + (size_t)L * C, nparam);
    k_cast<<<512, 256, 0, stream>>>(y, nparam, (L < 2) ? x32 : out);
  }
}